// Round 7
// baseline (161.680 us; speedup 1.0000x reference)
//
#include <hip/hip_runtime.h>

#define N_TOK 8192

typedef _Float16 f16x8 __attribute__((ext_vector_type(8)));
typedef _Float16 f16x4 __attribute__((ext_vector_type(4)));
typedef float    f32x4 __attribute__((ext_vector_type(4)));

__device__ __forceinline__ f32x4 mfma_k32(f16x8 a, f16x8 b, f32x4 c) {
  return __builtin_amdgcn_mfma_f32_16x16x32_f16(a, b, c, 0, 0, 0);
}
// Legacy K=16 MFMA: B-frag layout B[k=quad*4+b][col=l15] matches the K=32
// C layout (rows quad*4+r in regs) exactly -> P feeds PV with NO transpose.
__device__ __forceinline__ f32x4 mfma_k16(f16x4 a, f16x4 b, f32x4 c) {
  return __builtin_amdgcn_mfma_f32_16x16x16f16(a, b, c, 0, 0, 0);
}

// QSCALE^2 = log2(e)/sqrt(32); fold softmax scale + ln->log2 into q so
// s2[n,m] = qe_n . qe_m is directly the exp2 exponent.
#define QSCALE 0.50500977f

// ---------------------------------------------------------------------------
// Kernel A (prep): 256 blocks x 1024 thr; block b owns n-slice n0=b*32.
// Emits qe slice, blocked vht slice, seeds out with x, zeroes Ln + barrier
// counter. vht[nblk][c][inner32]: inner pos = q*8+h*4+r for n_local =
// h*16+q*4+r; a lane's f16x8 at inner q*8 holds the two K=16 PV A-frags.
// ---------------------------------------------------------------------------
__global__ __launch_bounds__(1024) void prep_kernel(
    const float* __restrict__ x, const float* __restrict__ W,
    const float* __restrict__ bias, _Float16* __restrict__ qe,
    _Float16* __restrict__ vht, float* __restrict__ Ln,
    int* __restrict__ cnt, float* __restrict__ out) {
  __shared__ float Wl[32 * 65];
  __shared__ float xl[64 * 36];
  int t = threadIdx.x, b = blockIdx.x;
  int n0 = b * 32;
  if (b < 8) Ln[b * 1024 + t] = 0.f;   // zero softmax-denominator accum
  if (b == 8 && t == 0) *cnt = 0;      // zero barrier counter
  for (int i = t; i < 2048; i += 1024) Wl[(i >> 6) * 65 + (i & 63)] = W[i];
  if (t < 512) {
    int c = t >> 3, j4 = t & 7;  // j4 = n_local/4
    f32x4 v = *(const f32x4*)(x + c * N_TOK + n0 + j4 * 4);
    *(f32x4*)&xl[c * 36 + j4 * 4] = v;
    *(f32x4*)(out + c * N_TOK + n0 + j4 * 4) = v;  // seed out = x
    f16x4 hv;
#pragma unroll
    for (int j = 0; j < 4; ++j) hv[j] = (_Float16)v[j];
    int q = j4 & 3, h = j4 >> 2;
    *(f16x4*)(vht + b * 2048 + c * 32 + q * 8 + h * 4) = hv;
  }
  __syncthreads();
  int nl = t >> 5, o = t & 31;
  float a0 = bias[o], a1 = 0.f;
#pragma unroll
  for (int c = 0; c < 32; ++c) {
    a0 = fmaf(Wl[o * 65 + c], xl[c * 36 + nl], a0);
    a1 = fmaf(Wl[o * 65 + 32 + c], xl[(32 + c) * 36 + nl], a1);
  }
  qe[(n0 + nl) * 32 + o] = (_Float16)((a0 + a1) * QSCALE);
}

// ---------------------------------------------------------------------------
// Kernel B (mega): phase 1 (softmax denominators) -> device spin barrier ->
// phase 2 (PV + output atomics). 256 blocks x 1024 thr, 1 block/CU (83 KB
// LDS) -> all blocks co-resident -> spin barrier is deadlock-free.
// Block b: rt = b>>1 (row-tile in ph1 / m-tile in ph2), half = b&1
// (m-half in ph1 / n-half in ph2; b%8 parity => one half per XCD's L2).
// Ln coherence: pre-barrier only device-scope atomics touch Ln; post-barrier
// each block reads its half ONCE via __hip_atomic_load(AGENT) (bypasses the
// stale-zero L2 lines), storing Bl = -log2(Ln) in LDS. The -log2 is fed as
// the MFMA C-operand so s - Bn comes out of the matrix pipe directly.
// ---------------------------------------------------------------------------
__global__ __launch_bounds__(1024, 4) void mega_kernel(
    const _Float16* __restrict__ qe, const _Float16* __restrict__ vht,
    float* __restrict__ Ln, int* __restrict__ cnt, float* __restrict__ out) {
  __shared__ union {
    float Lp[16][64];  // phase 1 partials
    struct {
      float Bl[4096];        // -log2(Ln) for this n-half
      float Ot[4 * 64 * 65]; // combine: [4 sets][64 c][65 m]
    } p2;
  } sm;
  int t = threadIdx.x, b = blockIdx.x;
  int w = t >> 6, lane = t & 63, quad = lane >> 4, l15 = lane & 15;
  int rt = b >> 1, half = b & 1;

  // ---------------- Phase 1: Ln[n] += sum_{m in half} exp2(qe_n.qe_m)
  {
    int n0 = rt * 64;
    int mbase = half * 4096 + w * 256;
    f16x8 af[4];
#pragma unroll
    for (int g = 0; g < 4; ++g)
      af[g] = *(const f16x8*)(qe + (n0 + g * 16 + l15) * 32 + quad * 8);
    f32x4 sums[4];
#pragma unroll
    for (int g = 0; g < 4; ++g) sums[g] = f32x4{0.f, 0.f, 0.f, 0.f};
    for (int mt = 0; mt < 8; ++mt) {
      int m0 = mbase + mt * 32;
      f16x8 bf0 = *(const f16x8*)(qe + (m0 + l15) * 32 + quad * 8);
      f16x8 bf1 = *(const f16x8*)(qe + (m0 + 16 + l15) * 32 + quad * 8);
      f32x4 zero = {0.f, 0.f, 0.f, 0.f};
#pragma unroll
      for (int g = 0; g < 4; ++g) {
        f32x4 s0 = mfma_k32(af[g], bf0, zero);  // rows n0+g*16+quad*4+r
        f32x4 s1 = mfma_k32(af[g], bf1, zero);
#pragma unroll
        for (int r = 0; r < 4; ++r)
          sums[g][r] +=
              __builtin_amdgcn_exp2f(s0[r]) + __builtin_amdgcn_exp2f(s1[r]);
      }
    }
#pragma unroll
    for (int g = 0; g < 4; ++g)
#pragma unroll
      for (int r = 0; r < 4; ++r)
#pragma unroll
        for (int mask = 1; mask < 16; mask <<= 1)
          sums[g][r] += __shfl_xor(sums[g][r], mask, 64);
    if (l15 == 0) {
#pragma unroll
      for (int g = 0; g < 4; ++g)
        *(f32x4*)&sm.Lp[w][g * 16 + quad * 4] = sums[g];
    }
    __syncthreads();
    if (t < 64) {
      float L = 0.f;
#pragma unroll
      for (int ww = 0; ww < 16; ++ww) L += sm.Lp[ww][t];
      unsafeAtomicAdd(Ln + n0 + t, L);
    }
  }

  // ---------------- Device barrier (all 256 blocks co-resident)
  __threadfence();
  __syncthreads();
  if (t == 0) {
    __hip_atomic_fetch_add(cnt, 1, __ATOMIC_ACQ_REL, __HIP_MEMORY_SCOPE_AGENT);
    while (__hip_atomic_load(cnt, __ATOMIC_ACQUIRE,
                             __HIP_MEMORY_SCOPE_AGENT) < 256)
      __builtin_amdgcn_s_sleep(2);
  }
  __syncthreads();

  // ---------------- Bl = -log2(Ln) for this n-half, once, into LDS
  for (int i = t; i < 4096; i += 1024) {
    float L = __hip_atomic_load(Ln + half * 4096 + i, __ATOMIC_RELAXED,
                                __HIP_MEMORY_SCOPE_AGENT);
    sm.p2.Bl[i] = -__builtin_amdgcn_logf(L);  // v_log_f32 = log2
  }
  __syncthreads();

  // ---------------- Phase 2: out[c, m-tile] += sum_{n in half} vh*P
  {
    int m0 = rt * 64;
    int chalf = w >> 3, nseg = w & 7;
    int nbl0 = nseg * 512;       // local n within half
    int nhb = half * 4096;       // global half base

    f16x8 bm[4];
#pragma unroll
    for (int mt = 0; mt < 4; ++mt)
      bm[mt] = *(const f16x8*)(qe + (m0 + mt * 16 + l15) * 32 + quad * 8);

    f32x4 acc[2][4];
#pragma unroll
    for (int ct = 0; ct < 2; ++ct)
#pragma unroll
      for (int mt = 0; mt < 4; ++mt) acc[ct][mt] = f32x4{0.f, 0.f, 0.f, 0.f};

    for (int ch = 0; ch < 16; ++ch) {
      int nbl = nbl0 + ch * 32;
      int nb = nhb + nbl;
      f16x8 an0 = *(const f16x8*)(qe + (nb + l15) * 32 + quad * 8);
      f16x8 an1 = *(const f16x8*)(qe + (nb + 16 + l15) * 32 + quad * 8);
      f32x4 nBq0 = *(const f32x4*)&sm.p2.Bl[nbl + quad * 4];
      f32x4 nBq1 = *(const f32x4*)&sm.p2.Bl[nbl + 16 + quad * 4];
      const _Float16* vb =
          vht + (nb >> 5) * 2048 + chalf * 1024 + l15 * 32 + quad * 8;
      f16x8 av0 = *(const f16x8*)(vb);
      f16x8 av1 = *(const f16x8*)(vb + 512);  // +16 c rows
      f16x4 p0[4], p1[4];
#pragma unroll
      for (int mt = 0; mt < 4; ++mt) {
        // C = -Bn: MFMA emits s - Bn directly (no VALU subtract).
        f32x4 s0 = mfma_k32(an0, bm[mt], nBq0);  // n=nb+quad*4+r, m=mt*16+l15
        f32x4 s1 = mfma_k32(an1, bm[mt], nBq1);  // n=nb+16+quad*4+r
#pragma unroll
        for (int r = 0; r < 4; ++r) {
          p0[mt][r] = (_Float16)__builtin_amdgcn_exp2f(s0[r]);
          p1[mt][r] = (_Float16)__builtin_amdgcn_exp2f(s1[r]);
        }
      }
#pragma unroll
      for (int ct = 0; ct < 2; ++ct) {
        f16x8 av = (ct == 0) ? av0 : av1;
        f16x4 lo, hi;
#pragma unroll
        for (int j = 0; j < 4; ++j) {
          lo[j] = av[j];
          hi[j] = av[j + 4];
        }
#pragma unroll
        for (int mt = 0; mt < 4; ++mt) {
          acc[ct][mt] = mfma_k16(lo, p0[mt], acc[ct][mt]);
          acc[ct][mt] = mfma_k16(hi, p1[mt], acc[ct][mt]);
        }
      }
    }

    // Combine partials across 8 n-segments (8 -> 4 -> 1), then atomic out.
    __syncthreads();  // Bl reads done; reuse LDS region for Ot
    if (nseg < 4) {
#pragma unroll
      for (int ct = 0; ct < 2; ++ct)
#pragma unroll
        for (int mt = 0; mt < 4; ++mt)
#pragma unroll
          for (int r = 0; r < 4; ++r)
            sm.p2.Ot[(nseg * 64 + chalf * 32 + ct * 16 + quad * 4 + r) * 65 +
                     mt * 16 + l15] = acc[ct][mt][r];
    }
    __syncthreads();
    if (nseg >= 4) {
#pragma unroll
      for (int ct = 0; ct < 2; ++ct)
#pragma unroll
        for (int mt = 0; mt < 4; ++mt)
#pragma unroll
          for (int r = 0; r < 4; ++r)
            sm.p2.Ot[((nseg - 4) * 64 + chalf * 32 + ct * 16 + quad * 4 + r) *
                         65 + mt * 16 + l15] += acc[ct][mt][r];
    }
    __syncthreads();
    // 4096 outputs, 1024 threads -> 4 each; m consecutive across lanes.
    for (int idx = t; idx < 4096; idx += 1024) {
      int cc = idx >> 6, m = idx & 63;
      float v = 0.f;
#pragma unroll
      for (int s = 0; s < 4; ++s) v += sm.p2.Ot[(s * 64 + cc) * 65 + m];
      unsafeAtomicAdd(out + cc * N_TOK + m0 + m, v);
    }
  }
}

// ---------------------------------------------------------------------------
extern "C" void kernel_launch(void* const* d_in, const int* in_sizes, int n_in,
                              void* d_out, int out_size, void* d_ws,
                              size_t ws_size, hipStream_t stream) {
  const float* x = (const float*)d_in[0];     // [64][8192]
  const float* W = (const float*)d_in[1];     // [32][64]
  const float* bias = (const float*)d_in[2];  // [32]
  float* out = (float*)d_out;                 // [64][8192]

  char* ws = (char*)d_ws;
  _Float16* qe = (_Float16*)ws;                  // 8192*32*2 = 512 KB
  _Float16* vht = (_Float16*)(ws + 524288);      // blocked vh: 1 MB
  float* Ln = (float*)(ws + 1572864);            // 8192*4 = 32 KB
  int* cnt = (int*)(ws + 1605632);               // barrier counter

  prep_kernel<<<256, 1024, 0, stream>>>(x, W, bias, qe, vht, Ln, cnt, out);
  mega_kernel<<<256, 1024, 0, stream>>>(qe, vht, Ln, cnt, out);
}

// Round 8
// 160.052 us; speedup vs baseline: 1.0102x; 1.0102x over previous
//
#include <hip/hip_runtime.h>

#define N_TOK 8192

typedef _Float16 f16x8 __attribute__((ext_vector_type(8)));
typedef _Float16 f16x4 __attribute__((ext_vector_type(4)));
typedef float    f32x4 __attribute__((ext_vector_type(4)));

__device__ __forceinline__ f32x4 mfma_k32(f16x8 a, f16x8 b, f32x4 c) {
  return __builtin_amdgcn_mfma_f32_16x16x32_f16(a, b, c, 0, 0, 0);
}
// Legacy K=16 MFMA: B-frag layout B[k=quad*4+b][col=l15] matches the K=32
// C layout (rows quad*4+r in regs) exactly -> P feeds PV with NO transpose.
__device__ __forceinline__ f32x4 mfma_k16(f16x4 a, f16x4 b, f32x4 c) {
  return __builtin_amdgcn_mfma_f32_16x16x16f16(a, b, c, 0, 0, 0);
}

// QSCALE^2 = log2(e)/sqrt(32); fold softmax scale + ln->log2 into q so
// s2[n,m] = qe_n . qe_m is directly the exp2 exponent.
#define QSCALE 0.50500977f

// ---------------------------------------------------------------------------
// Kernel A (prep): 256 blocks x 1024 thr; block b owns n-slice n0=b*32.
// Emits qe slice, blocked vht slice, seeds out with x, zeroes Ln + barrier
// counter. vht[nblk][c][inner32]: inner pos = q*8+h*4+r for n_local =
// h*16+q*4+r; a lane's f16x8 at inner q*8 holds the two K=16 PV A-frags.
// (Ln/cnt zeroed with plain stores: the prep->mega kernel boundary writes
// back dirty L2, so mega's fabric atomics see the zeros. Verified r5/r6.)
// ---------------------------------------------------------------------------
__global__ __launch_bounds__(1024) void prep_kernel(
    const float* __restrict__ x, const float* __restrict__ W,
    const float* __restrict__ bias, _Float16* __restrict__ qe,
    _Float16* __restrict__ vht, float* __restrict__ Ln,
    int* __restrict__ cnt, float* __restrict__ out) {
  __shared__ float Wl[32 * 65];
  __shared__ float xl[64 * 36];
  int t = threadIdx.x, b = blockIdx.x;
  int n0 = b * 32;
  if (b < 8) Ln[b * 1024 + t] = 0.f;   // zero softmax-denominator accum
  if (b == 8 && t == 0) *cnt = 0;      // zero barrier counter
  for (int i = t; i < 2048; i += 1024) Wl[(i >> 6) * 65 + (i & 63)] = W[i];
  if (t < 512) {
    int c = t >> 3, j4 = t & 7;  // j4 = n_local/4
    f32x4 v = *(const f32x4*)(x + c * N_TOK + n0 + j4 * 4);
    *(f32x4*)&xl[c * 36 + j4 * 4] = v;
    *(f32x4*)(out + c * N_TOK + n0 + j4 * 4) = v;  // seed out = x
    f16x4 hv;
#pragma unroll
    for (int j = 0; j < 4; ++j) hv[j] = (_Float16)v[j];
    int q = j4 & 3, h = j4 >> 2;
    *(f16x4*)(vht + b * 2048 + c * 32 + q * 8 + h * 4) = hv;
  }
  __syncthreads();
  int nl = t >> 5, o = t & 31;
  float a0 = bias[o], a1 = 0.f;
#pragma unroll
  for (int c = 0; c < 32; ++c) {
    a0 = fmaf(Wl[o * 65 + c], xl[c * 36 + nl], a0);
    a1 = fmaf(Wl[o * 65 + 32 + c], xl[(32 + c) * 36 + nl], a1);
  }
  qe[(n0 + nl) * 32 + o] = (_Float16)((a0 + a1) * QSCALE);
}

// ---------------------------------------------------------------------------
// Kernel B (mega): phase 1 (softmax denominators) -> device spin barrier ->
// phase 2 (PV + output atomics). 256 blocks x 1024 thr, 1 block/CU (83 KB
// LDS) -> all blocks co-resident -> spin barrier is deadlock-free.
// BARRIER FIX vs round 7: poll with RELAXED (acquire-per-poll emitted a
// cache invalidate every iteration -> 8-XCD invalidate storm, evicting the
// phase-1 working set and stretching the wait; ~80us of stall). Ordering
// is still correct: each block's Ln atomicAdds (fabric-coherent) complete
// before its RELEASE arrive (threadfence + release waits vmcnt); the
// waiter reads Ln via agent-scope atomic loads that bypass stale L2.
// The -log2(Ln) is fed as the MFMA C-operand (free subtract).
// ---------------------------------------------------------------------------
__global__ __launch_bounds__(1024, 4) void mega_kernel(
    const _Float16* __restrict__ qe, const _Float16* __restrict__ vht,
    float* __restrict__ Ln, int* __restrict__ cnt, float* __restrict__ out) {
  __shared__ union {
    float Lp[16][64];  // phase 1 partials
    struct {
      float Bl[4096];        // -log2(Ln) for this n-half
      float Ot[4 * 64 * 65]; // combine: [4 sets][64 c][65 m]
    } p2;
  } sm;
  int t = threadIdx.x, b = blockIdx.x;
  int w = t >> 6, lane = t & 63, quad = lane >> 4, l15 = lane & 15;
  int rt = b >> 1, half = b & 1;

  // ---------------- Phase 1: Ln[n] += sum_{m in half} exp2(qe_n.qe_m)
  {
    int n0 = rt * 64;
    int mbase = half * 4096 + w * 256;
    f16x8 af[4];
#pragma unroll
    for (int g = 0; g < 4; ++g)
      af[g] = *(const f16x8*)(qe + (n0 + g * 16 + l15) * 32 + quad * 8);
    f32x4 sums[4];
#pragma unroll
    for (int g = 0; g < 4; ++g) sums[g] = f32x4{0.f, 0.f, 0.f, 0.f};
    for (int mt = 0; mt < 8; ++mt) {
      int m0 = mbase + mt * 32;
      f16x8 bf0 = *(const f16x8*)(qe + (m0 + l15) * 32 + quad * 8);
      f16x8 bf1 = *(const f16x8*)(qe + (m0 + 16 + l15) * 32 + quad * 8);
      f32x4 zero = {0.f, 0.f, 0.f, 0.f};
#pragma unroll
      for (int g = 0; g < 4; ++g) {
        f32x4 s0 = mfma_k32(af[g], bf0, zero);  // rows n0+g*16+quad*4+r
        f32x4 s1 = mfma_k32(af[g], bf1, zero);
#pragma unroll
        for (int r = 0; r < 4; ++r)
          sums[g][r] +=
              __builtin_amdgcn_exp2f(s0[r]) + __builtin_amdgcn_exp2f(s1[r]);
      }
    }
#pragma unroll
    for (int g = 0; g < 4; ++g)
#pragma unroll
      for (int r = 0; r < 4; ++r)
#pragma unroll
        for (int mask = 1; mask < 16; mask <<= 1)
          sums[g][r] += __shfl_xor(sums[g][r], mask, 64);
    if (l15 == 0) {
#pragma unroll
      for (int g = 0; g < 4; ++g)
        *(f32x4*)&sm.Lp[w][g * 16 + quad * 4] = sums[g];
    }
    __syncthreads();
    if (t < 64) {
      float L = 0.f;
#pragma unroll
      for (int ww = 0; ww < 16; ++ww) L += sm.Lp[ww][t];
      unsafeAtomicAdd(Ln + n0 + t, L);
    }
  }

  // ---------------- Device barrier (all 256 blocks co-resident)
  __threadfence();   // drain this block's Ln atomics before arrive
  __syncthreads();
  if (t == 0) {
    __hip_atomic_fetch_add(cnt, 1, __ATOMIC_RELEASE, __HIP_MEMORY_SCOPE_AGENT);
    while (__hip_atomic_load(cnt, __ATOMIC_RELAXED,
                             __HIP_MEMORY_SCOPE_AGENT) < 256)
      __builtin_amdgcn_s_sleep(16);  // relaxed poll: no invalidate storm
  }
  __syncthreads();

  // ---------------- Bl = -log2(Ln) for this n-half, once, into LDS
  for (int i = t; i < 4096; i += 1024) {
    float L = __hip_atomic_load(Ln + half * 4096 + i, __ATOMIC_RELAXED,
                                __HIP_MEMORY_SCOPE_AGENT);
    sm.p2.Bl[i] = -__builtin_amdgcn_logf(L);  // v_log_f32 = log2
  }
  __syncthreads();

  // ---------------- Phase 2: out[c, m-tile] += sum_{n in half} vh*P
  {
    int m0 = rt * 64;
    int chalf = w >> 3, nseg = w & 7;
    int nbl0 = nseg * 512;       // local n within half
    int nhb = half * 4096;       // global half base

    f16x8 bm[4];
#pragma unroll
    for (int mt = 0; mt < 4; ++mt)
      bm[mt] = *(const f16x8*)(qe + (m0 + mt * 16 + l15) * 32 + quad * 8);

    f32x4 acc[2][4];
#pragma unroll
    for (int ct = 0; ct < 2; ++ct)
#pragma unroll
      for (int mt = 0; mt < 4; ++mt) acc[ct][mt] = f32x4{0.f, 0.f, 0.f, 0.f};

    for (int ch = 0; ch < 16; ++ch) {
      int nbl = nbl0 + ch * 32;
      int nb = nhb + nbl;
      f16x8 an0 = *(const f16x8*)(qe + (nb + l15) * 32 + quad * 8);
      f16x8 an1 = *(const f16x8*)(qe + (nb + 16 + l15) * 32 + quad * 8);
      f32x4 nBq0 = *(const f32x4*)&sm.p2.Bl[nbl + quad * 4];
      f32x4 nBq1 = *(const f32x4*)&sm.p2.Bl[nbl + 16 + quad * 4];
      const _Float16* vb =
          vht + (nb >> 5) * 2048 + chalf * 1024 + l15 * 32 + quad * 8;
      f16x8 av0 = *(const f16x8*)(vb);
      f16x8 av1 = *(const f16x8*)(vb + 512);  // +16 c rows
      f16x4 p0[4], p1[4];
#pragma unroll
      for (int mt = 0; mt < 4; ++mt) {
        // C = -Bn: MFMA emits s - Bn directly (no VALU subtract).
        f32x4 s0 = mfma_k32(an0, bm[mt], nBq0);  // n=nb+quad*4+r, m=mt*16+l15
        f32x4 s1 = mfma_k32(an1, bm[mt], nBq1);  // n=nb+16+quad*4+r
#pragma unroll
        for (int r = 0; r < 4; ++r) {
          p0[mt][r] = (_Float16)__builtin_amdgcn_exp2f(s0[r]);
          p1[mt][r] = (_Float16)__builtin_amdgcn_exp2f(s1[r]);
        }
      }
#pragma unroll
      for (int ct = 0; ct < 2; ++ct) {
        f16x8 av = (ct == 0) ? av0 : av1;
        f16x4 lo, hi;
#pragma unroll
        for (int j = 0; j < 4; ++j) {
          lo[j] = av[j];
          hi[j] = av[j + 4];
        }
#pragma unroll
        for (int mt = 0; mt < 4; ++mt) {
          acc[ct][mt] = mfma_k16(lo, p0[mt], acc[ct][mt]);
          acc[ct][mt] = mfma_k16(hi, p1[mt], acc[ct][mt]);
        }
      }
    }

    // Combine partials across 8 n-segments (8 -> 4 -> 1), then atomic out.
    __syncthreads();  // Bl reads done; Ot region is separate but reuse-safe
    if (nseg < 4) {
#pragma unroll
      for (int ct = 0; ct < 2; ++ct)
#pragma unroll
        for (int mt = 0; mt < 4; ++mt)
#pragma unroll
          for (int r = 0; r < 4; ++r)
            sm.p2.Ot[(nseg * 64 + chalf * 32 + ct * 16 + quad * 4 + r) * 65 +
                     mt * 16 + l15] = acc[ct][mt][r];
    }
    __syncthreads();
    if (nseg >= 4) {
#pragma unroll
      for (int ct = 0; ct < 2; ++ct)
#pragma unroll
        for (int mt = 0; mt < 4; ++mt)
#pragma unroll
          for (int r = 0; r < 4; ++r)
            sm.p2.Ot[((nseg - 4) * 64 + chalf * 32 + ct * 16 + quad * 4 + r) *
                         65 + mt * 16 + l15] += acc[ct][mt][r];
    }
    __syncthreads();
    // 4096 outputs, 1024 threads -> 4 each; m consecutive across lanes.
    for (int idx = t; idx < 4096; idx += 1024) {
      int cc = idx >> 6, m = idx & 63;
      float v = 0.f;
#pragma unroll
      for (int s = 0; s < 4; ++s) v += sm.p2.Ot[(s * 64 + cc) * 65 + m];
      unsafeAtomicAdd(out + cc * N_TOK + m0 + m, v);
    }
  }
}

// ---------------------------------------------------------------------------
extern "C" void kernel_launch(void* const* d_in, const int* in_sizes, int n_in,
                              void* d_out, int out_size, void* d_ws,
                              size_t ws_size, hipStream_t stream) {
  const float* x = (const float*)d_in[0];     // [64][8192]
  const float* W = (const float*)d_in[1];     // [32][64]
  const float* bias = (const float*)d_in[2];  // [32]
  float* out = (float*)d_out;                 // [64][8192]

  char* ws = (char*)d_ws;
  _Float16* qe = (_Float16*)ws;                  // 8192*32*2 = 512 KB
  _Float16* vht = (_Float16*)(ws + 524288);      // blocked vh: 1 MB
  float* Ln = (float*)(ws + 1572864);            // 8192*4 = 32 KB
  int* cnt = (int*)(ws + 1605632);               // barrier counter

  prep_kernel<<<256, 1024, 0, stream>>>(x, W, bias, qe, vht, Ln, cnt, out);
  mega_kernel<<<256, 1024, 0, stream>>>(qe, vht, Ln, cnt, out);
}

// Round 9
// 99.440 us; speedup vs baseline: 1.6259x; 1.6095x over previous
//
#include <hip/hip_runtime.h>

#define N_TOK 8192

typedef _Float16 f16x8 __attribute__((ext_vector_type(8)));
typedef _Float16 f16x4 __attribute__((ext_vector_type(4)));
typedef float    f32x4 __attribute__((ext_vector_type(4)));

__device__ __forceinline__ f32x4 mfma_k32(f16x8 a, f16x8 b, f32x4 c) {
  return __builtin_amdgcn_mfma_f32_16x16x32_f16(a, b, c, 0, 0, 0);
}
// Legacy K=16 MFMA: B-frag layout B[k=quad*4+b][col=l15] matches the K=32
// C layout (rows quad*4+r in regs) exactly -> P feeds PV with NO transpose.
__device__ __forceinline__ f32x4 mfma_k16(f16x4 a, f16x4 b, f32x4 c) {
  return __builtin_amdgcn_mfma_f32_16x16x16f16(a, b, c, 0, 0, 0);
}

// QSCALE^2 = log2(e)/sqrt(32); fold softmax scale + ln->log2 into q so
// s2[n,m] = qe_n . qe_m is directly the exp2 exponent.
#define QSCALE 0.50500977f

// ---------------------------------------------------------------------------
// Kernel A (prep): 256 blocks x 1024 thr; block b owns n-slice n0=b*32.
// Emits qe slice, blocked vht slice, seeds out with x, zeroes Ln.
// vht[nblk][c][inner32]: inner pos = q*8+h*4+r for n_local = h*16+q*4+r;
// a lane's f16x8 at inner q*8 holds the two K=16 PV A-frags.
// ---------------------------------------------------------------------------
__global__ __launch_bounds__(1024) void prep_kernel(
    const float* __restrict__ x, const float* __restrict__ W,
    const float* __restrict__ bias, _Float16* __restrict__ qe,
    _Float16* __restrict__ vht, float* __restrict__ Ln,
    float* __restrict__ out) {
  __shared__ float Wl[32 * 65];
  __shared__ float xl[64 * 36];
  int t = threadIdx.x, b = blockIdx.x;
  int n0 = b * 32;
  if (b < 8) Ln[b * 1024 + t] = 0.f;  // zero softmax-denominator accum
  for (int i = t; i < 2048; i += 1024) Wl[(i >> 6) * 65 + (i & 63)] = W[i];
  if (t < 512) {
    int c = t >> 3, j4 = t & 7;  // j4 = n_local/4
    f32x4 v = *(const f32x4*)(x + c * N_TOK + n0 + j4 * 4);
    *(f32x4*)&xl[c * 36 + j4 * 4] = v;
    *(f32x4*)(out + c * N_TOK + n0 + j4 * 4) = v;  // seed out = x
    f16x4 hv;
#pragma unroll
    for (int j = 0; j < 4; ++j) hv[j] = (_Float16)v[j];
    int q = j4 & 3, h = j4 >> 2;
    *(f16x4*)(vht + b * 2048 + c * 32 + q * 8 + h * 4) = hv;
  }
  __syncthreads();
  int nl = t >> 5, o = t & 31;
  float a0 = bias[o], a1 = 0.f;
#pragma unroll
  for (int c = 0; c < 32; ++c) {
    a0 = fmaf(Wl[o * 65 + c], xl[c * 36 + nl], a0);
    a1 = fmaf(Wl[o * 65 + 32 + c], xl[(32 + c) * 36 + nl], a1);
  }
  qe[(n0 + nl) * 32 + o] = (_Float16)((a0 + a1) * QSCALE);
}

// ---------------------------------------------------------------------------
// Kernel B (pass 1): Ln[n] += sum_{m in m-half} exp2(qe_n . qe_m)
// 256 blocks = 128 row-tiles (64 n) x 2 m-halves; 16 waves split the 4096-m
// half 16 ways. Partial row-sums are exp-space additive -> unsafeAtomicAdd.
// (Verified round 6.)
// ---------------------------------------------------------------------------
__global__ __launch_bounds__(1024) void pass1_kernel(
    const _Float16* __restrict__ qe, float* __restrict__ Ln) {
  __shared__ float Lp[16][64];
  int t = threadIdx.x, b = blockIdx.x;
  int w = t >> 6, lane = t & 63, quad = lane >> 4, l15 = lane & 15;
  int n0 = (b >> 1) * 64;
  int mbase = (b & 1) * 4096 + w * 256;
  f16x8 af[4];
#pragma unroll
  for (int g = 0; g < 4; ++g)
    af[g] = *(const f16x8*)(qe + (n0 + g * 16 + l15) * 32 + quad * 8);
  f32x4 sums[4];
#pragma unroll
  for (int g = 0; g < 4; ++g) sums[g] = f32x4{0.f, 0.f, 0.f, 0.f};
  for (int mt = 0; mt < 8; ++mt) {
    int m0 = mbase + mt * 32;
    f16x8 bf0 = *(const f16x8*)(qe + (m0 + l15) * 32 + quad * 8);
    f16x8 bf1 = *(const f16x8*)(qe + (m0 + 16 + l15) * 32 + quad * 8);
    f32x4 zero = {0.f, 0.f, 0.f, 0.f};
#pragma unroll
    for (int g = 0; g < 4; ++g) {
      f32x4 s0 = mfma_k32(af[g], bf0, zero);  // rows n0+g*16+quad*4+r
      f32x4 s1 = mfma_k32(af[g], bf1, zero);
#pragma unroll
      for (int r = 0; r < 4; ++r)
        sums[g][r] +=
            __builtin_amdgcn_exp2f(s0[r]) + __builtin_amdgcn_exp2f(s1[r]);
    }
  }
  // reduce across the 16 m-columns (l15 = lane bits 0..3)
#pragma unroll
  for (int g = 0; g < 4; ++g)
#pragma unroll
    for (int r = 0; r < 4; ++r)
#pragma unroll
      for (int mask = 1; mask < 16; mask <<= 1)
        sums[g][r] += __shfl_xor(sums[g][r], mask, 64);
  if (l15 == 0) {
#pragma unroll
    for (int g = 0; g < 4; ++g)
      *(f32x4*)&Lp[w][g * 16 + quad * 4] = sums[g];
  }
  __syncthreads();
  if (t < 64) {
    float L = 0.f;
#pragma unroll
    for (int ww = 0; ww < 16; ++ww) L += Lp[ww][t];
    unsafeAtomicAdd(Ln + n0 + t, L);
  }
}

// ---------------------------------------------------------------------------
// Kernel C (pass 2): out[c,m] += sum_{n in half} vh[c,n]*exp2(s_nm - Bn[n])
// 256 blocks = 128 m-tiles (64 m) x 2 n-halves. 16 waves = 8 n-segs x
// 2 M-HALVES, each wave owns ALL 64 c -> every P element (exp2) and every
// S-MFMA computed exactly ONCE per block (round-6's c-half split duplicated
// both 2x; exp2 issue cost is unhideable, the extra vht L2 reads are not).
// Bl = -log2(Ln) preloaded to LDS once; fed as MFMA C-operand so s - Bn
// comes out of the matrix pipe (no VALU subtract). Verified rounds 7/8.
// ---------------------------------------------------------------------------
__global__ __launch_bounds__(1024, 4) void pass2_kernel(
    const _Float16* __restrict__ qe, const _Float16* __restrict__ vht,
    const float* __restrict__ Ln, float* __restrict__ out) {
  __shared__ float Bl[4096];         // -log2(Ln) for this n-half
  __shared__ float Ot[4 * 64 * 65];  // combine: [4 sets][64 c][65 m]
  int t = threadIdx.x, b = blockIdx.x;
  int w = t >> 6, lane = t & 63, quad = lane >> 4, l15 = lane & 15;
  int m0 = (b >> 1) * 64;  // 64-m tile
  int half = b & 1;        // n-half
  int nseg = w >> 1, mhalf = w & 1;
  int nhb = half * 4096, nbl0 = nseg * 512;

  // Bl once per block (plain loads: pass1->pass2 kernel boundary makes the
  // Ln atomics visible; verified rounds 5/6).
  for (int i = t; i < 4096; i += 1024)
    Bl[i] = -__builtin_amdgcn_logf(Ln[nhb + i]);  // v_log_f32 = log2
  __syncthreads();

  // B frags: this wave's 32 m-columns (mhalf half of the 64-m tile)
  f16x8 bm[2];
#pragma unroll
  for (int mt = 0; mt < 2; ++mt)
    bm[mt] =
        *(const f16x8*)(qe + (m0 + mhalf * 32 + mt * 16 + l15) * 32 + quad * 8);

  f32x4 acc[4][2];
#pragma unroll
  for (int ct = 0; ct < 4; ++ct)
#pragma unroll
    for (int mt = 0; mt < 2; ++mt) acc[ct][mt] = f32x4{0.f, 0.f, 0.f, 0.f};

  for (int ch = 0; ch < 16; ++ch) {
    int nbl = nbl0 + ch * 32;
    int nb = nhb + nbl;
    f16x8 an0 = *(const f16x8*)(qe + (nb + l15) * 32 + quad * 8);
    f16x8 an1 = *(const f16x8*)(qe + (nb + 16 + l15) * 32 + quad * 8);
    f32x4 nBq0 = *(const f32x4*)&Bl[nbl + quad * 4];
    f32x4 nBq1 = *(const f32x4*)&Bl[nbl + 16 + quad * 4];
    const _Float16* vb = vht + (nb >> 5) * 2048 + l15 * 32 + quad * 8;
    f16x8 av[4];
#pragma unroll
    for (int ct = 0; ct < 4; ++ct)
      av[ct] = *(const f16x8*)(vb + ct * 512);  // c = ct*16 + l15
#pragma unroll
    for (int mt = 0; mt < 2; ++mt) {
      // C = -Bn: MFMA emits s - Bn directly.
      f32x4 s0 = mfma_k32(an0, bm[mt], nBq0);  // n=nb+quad*4+r
      f32x4 s1 = mfma_k32(an1, bm[mt], nBq1);  // n=nb+16+quad*4+r
      f16x4 p0, p1;
#pragma unroll
      for (int r = 0; r < 4; ++r) {
        p0[r] = (_Float16)__builtin_amdgcn_exp2f(s0[r]);
        p1[r] = (_Float16)__builtin_amdgcn_exp2f(s1[r]);
      }
#pragma unroll
      for (int ct = 0; ct < 4; ++ct) {
        f16x4 lo, hi;
#pragma unroll
        for (int j = 0; j < 4; ++j) {
          lo[j] = av[ct][j];
          hi[j] = av[ct][j + 4];
        }
        acc[ct][mt] = mfma_k16(lo, p0, acc[ct][mt]);
        acc[ct][mt] = mfma_k16(hi, p1, acc[ct][mt]);
      }
    }
  }

  // Combine partials across 8 n-segments (8 -> 4 -> 1), then atomic out.
  // mhalf pairs write disjoint m-columns; sets indexed by nseg.
  __syncthreads();
  if (nseg < 4) {
#pragma unroll
    for (int ct = 0; ct < 4; ++ct)
#pragma unroll
      for (int mt = 0; mt < 2; ++mt)
#pragma unroll
        for (int r = 0; r < 4; ++r)
          Ot[(nseg * 64 + ct * 16 + quad * 4 + r) * 65 + mhalf * 32 +
             mt * 16 + l15] = acc[ct][mt][r];
  }
  __syncthreads();
  if (nseg >= 4) {
#pragma unroll
    for (int ct = 0; ct < 4; ++ct)
#pragma unroll
      for (int mt = 0; mt < 2; ++mt)
#pragma unroll
        for (int r = 0; r < 4; ++r)
          Ot[((nseg - 4) * 64 + ct * 16 + quad * 4 + r) * 65 + mhalf * 32 +
             mt * 16 + l15] += acc[ct][mt][r];
  }
  __syncthreads();
  // 4096 outputs, 1024 threads -> 4 each; m consecutive across lanes.
  for (int idx = t; idx < 4096; idx += 1024) {
    int cc = idx >> 6, m = idx & 63;
    float v = 0.f;
#pragma unroll
    for (int s = 0; s < 4; ++s) v += Ot[(s * 64 + cc) * 65 + m];
    unsafeAtomicAdd(out + cc * N_TOK + m0 + m, v);
  }
}

// ---------------------------------------------------------------------------
extern "C" void kernel_launch(void* const* d_in, const int* in_sizes, int n_in,
                              void* d_out, int out_size, void* d_ws,
                              size_t ws_size, hipStream_t stream) {
  const float* x = (const float*)d_in[0];     // [64][8192]
  const float* W = (const float*)d_in[1];     // [32][64]
  const float* bias = (const float*)d_in[2];  // [32]
  float* out = (float*)d_out;                 // [64][8192]

  char* ws = (char*)d_ws;
  _Float16* qe = (_Float16*)ws;              // 8192*32*2 = 512 KB
  _Float16* vht = (_Float16*)(ws + 524288);  // blocked vh: 1 MB
  float* Ln = (float*)(ws + 1572864);        // 8192*4 = 32 KB

  prep_kernel<<<256, 1024, 0, stream>>>(x, W, bias, qe, vht, Ln, out);
  pass1_kernel<<<256, 1024, 0, stream>>>(qe, Ln);
  pass2_kernel<<<256, 1024, 0, stream>>>(qe, vht, Ln, out);
}